// Round 5
// baseline (252.600 us; speedup 1.0000x reference)
//
#include <hip/hip_runtime.h>

#define B_ 8
#define C_ 256
#define I_ 128
#define N_ 4096
#define BN_ (B_ * N_)
#define LOG2E 1.4426950408889634f

typedef __attribute__((ext_vector_type(8))) short bf16x8;
typedef __attribute__((ext_vector_type(4))) float f32x4;
typedef __attribute__((ext_vector_type(4))) int i32x4;

static __device__ __forceinline__ short f2bf(float f) {
    unsigned u = __float_as_uint(f);
    unsigned r = u + 0x7fffu + ((u >> 16) & 1u);  // RNE
    return (short)(r >> 16);
}
static __device__ __forceinline__ float bf2f(short s) {
    return __uint_as_float(((unsigned)(unsigned short)s) << 16);
}
static __device__ __forceinline__ unsigned cvt_pk_bf16(float lo, float hi) {
    unsigned r;
    asm("v_cvt_pk_bf16_f32 %0, %1, %2" : "=v"(r) : "v"(lo), "v"(hi));
    return r;
}
// async global->LDS, 16B/lane; LDS dest is wave-uniform base + lane*16,
// global src is per-lane (carries the inverse swizzle).
static __device__ __forceinline__ void async_copy16(const void* g, void* l) {
    __builtin_amdgcn_global_load_lds(
        (const __attribute__((address_space(1))) void*)g,
        (__attribute__((address_space(3))) void*)l, 16, 0, 0);
}

// ---------------- K0: weight prep (theta scaled by log2e) + bnsum zero -------
__global__ void k_prep(const float* g_w, const float* theta_w, const float* phi_w,
                       const float* g_b, const float* theta_b, const float* phi_b,
                       const float* w_w, short* wcat, short* wwb, float* bcat,
                       float* bnsum) {
    int i = blockIdx.x * 256 + threadIdx.x;
    if (i < 384 * 256) {
        int j = i >> 8, c = i & 255;
        float v = (j < 128) ? theta_w[j * 256 + c] * LOG2E
                : (j < 256) ? phi_w[(j - 128) * 256 + c]
                            : g_w[(j - 256) * 256 + c];
        wcat[i] = f2bf(v);
    } else if (i < 384 * 256 + 256 * 128) {
        int k = i - 384 * 256;
        wwb[k] = f2bf(w_w[k]);
    } else if (i < 384 * 256 + 256 * 128 + 384) {
        int j = i - (384 * 256 + 256 * 128);
        bcat[j] = (j < 128) ? theta_b[j] * LOG2E
                : (j < 256) ? phi_b[j - 128] : g_b[j - 256];
    } else if (i < 384 * 256 + 256 * 128 + 384 + 512) {
        bnsum[i - (384 * 256 + 256 * 128 + 384)] = 0.f;
    }
}

// ---------------- K1: projection -> tp[B][N][256], gmat[B][I][N] ---
__global__ __launch_bounds__(256) void k_proj(const float* __restrict__ x,
                                              const short* __restrict__ wcat,
                                              const float* __restrict__ bcat,
                                              short* __restrict__ tp,
                                              short* __restrict__ gmat) {
    int b = blockIdx.y;
    int n0 = blockIdx.x * 64;
    int tid = threadIdx.x;
    int wave = tid >> 6, lane = tid & 63, s = lane & 15, q = lane >> 4;
    __shared__ short xs[64][264];  // [n-local][c]

#pragma unroll
    for (int it = 0; it < 16; ++it) {
        int cr = (tid >> 4) + it * 16;
        int nc = tid & 15;
        const float4 v = *(const float4*)&x[((size_t)b * C_ + cr) * N_ + n0 + nc * 4];
        xs[nc * 4 + 0][cr] = f2bf(v.x);
        xs[nc * 4 + 1][cr] = f2bf(v.y);
        xs[nc * 4 + 2][cr] = f2bf(v.z);
        xs[nc * 4 + 3][cr] = f2bf(v.w);
    }
    __syncthreads();

    f32x4 acc[4][6];
#pragma unroll
    for (int rt = 0; rt < 4; ++rt)
#pragma unroll
        for (int jt = 0; jt < 6; ++jt) acc[rt][jt] = (f32x4){0.f, 0.f, 0.f, 0.f};

#pragma unroll
    for (int kb = 0; kb < 8; ++kb) {
        bf16x8 af[4], bfv[6];
#pragma unroll
        for (int rt = 0; rt < 4; ++rt)
            af[rt] = *(const bf16x8*)&xs[rt * 16 + s][kb * 32 + q * 8];
#pragma unroll
        for (int jt = 0; jt < 6; ++jt)
            bfv[jt] = *(const bf16x8*)&wcat[(wave * 96 + jt * 16 + s) * 256 + kb * 32 + q * 8];
#pragma unroll
        for (int rt = 0; rt < 4; ++rt)
#pragma unroll
            for (int jt = 0; jt < 6; ++jt)
                acc[rt][jt] = __builtin_amdgcn_mfma_f32_16x16x32_bf16(af[rt], bfv[jt], acc[rt][jt], 0, 0, 0);
    }

#pragma unroll
    for (int rt = 0; rt < 4; ++rt)
#pragma unroll
        for (int jt = 0; jt < 6; ++jt) {
            int j = wave * 96 + jt * 16 + s;
            float bias = bcat[j];
#pragma unroll
            for (int r = 0; r < 4; ++r) {
                int n = n0 + rt * 16 + 4 * q + r;
                float v = acc[rt][jt][r] + bias;
                if (j < 256)
                    tp[((size_t)b * N_ + n) * 256 + j] = f2bf(v);
                else
                    gmat[((size_t)b * I_ + (j - 256)) * N_ + n] = f2bf(v);
            }
        }
}

// ---- K2: fused flash attention + conv-out GEMM + BN-stat atomics ------------
// 256 blocks x 512 threads; Q-tile 128, all 4096 keys, dbuf 128KB LDS.
// Wave layout G_q=4 x G_k=2. Staging via global_load_lds: LDS dest linear,
// global source carries the inverse XOR swizzle per-lane (rule: both-sides-
// or-neither); no ds_writes, no staging VGPRs, loads hide under full compute.
// Epilogue: kg cross-reduction -> y bf16 -> in-block wy GEMM -> wyh, plus
// per-channel s1/s2 shfl-reduced + atomicAdd into bnsum (k_stats eliminated).
__global__ __launch_bounds__(512, 2) void k_attn_wy(const short* __restrict__ tp,
                                                    const short* __restrict__ gmat,
                                                    const short* __restrict__ wwb,
                                                    const float* __restrict__ w_b,
                                                    short* __restrict__ wyh,
                                                    float* __restrict__ bnsum) {
    int id = blockIdx.x;
    int b = id & 7;               // XCD swizzle: one batch's K/V per XCD L2
    int qt = id >> 3;             // 0..31
    int n0 = qt * 128;
    int tid = threadIdx.x;
    int wave = tid >> 6, lane = tid & 63, s = lane & 15, q = lane >> 4;
    int kg = wave >> 2, qg = wave & 3;

    // 2 bufs x (Kt[128key][128i] 32KB + Vt[128i][128key] 32KB) = 128KB, swizzled
    __shared__ __align__(16) short SH[65536];
    __shared__ float l_lds[2][128];
    char* base = (char*)SH;

    const int swz = (s & 7) << 4;
    int kA[4];
#pragma unroll
    for (int kb = 0; kb < 4; ++kb) kA[kb] = s * 256 + ((kb * 64 + q * 16) ^ swz);
    int vA[2];
#pragma unroll
    for (int kb2 = 0; kb2 < 2; ++kb2) vA[kb2] = s * 256 + ((kb2 * 64 + q * 16) ^ swz);

    // async staging: wave w, round it stages rows it*32 + w*4 + (lane>>4);
    // source column pre-inverse-swizzled by (row&7)<<4.
    int rl = lane >> 4;
    int colS = ((lane & 15) * 16) ^ ((((wave & 1) << 2) | rl) << 4);
    const char* gK = (const char*)tp + ((size_t)b * N_ + wave * 4 + rl) * 512 + 256 + colS;
    const char* gV = (const char*)gmat + ((size_t)b * I_ + wave * 4 + rl) * 8192 + colS;
    const int ldsSt = wave * 1024;  // wave-uniform dest offset

    // ones B-frag for l-accumulation MFMA
    i32x4 onesw = (i32x4){0x3F803F80, 0x3F803F80, 0x3F803F80, 0x3F803F80};
    bf16x8 vone = __builtin_bit_cast(bf16x8, onesw);

    // Q fragments (B-operand of S^T): queries n0 + qg*32 + fr*16 + s
    bf16x8 qf[2][4];
#pragma unroll
    for (int fr = 0; fr < 2; ++fr) {
        const short* qb = tp + ((size_t)b * N_ + n0 + qg * 32 + fr * 16 + s) * 256;
#pragma unroll
        for (int kb = 0; kb < 4; ++kb) qf[fr][kb] = *(const bf16x8*)(qb + kb * 32 + q * 8);
    }

    f32x4 ot[2][8];  // O partial (kg's key half): rows=query 4q+r, cols i=t*16+s
#pragma unroll
    for (int fr = 0; fr < 2; ++fr)
#pragma unroll
        for (int t = 0; t < 8; ++t) ot[fr][t] = (f32x4){0.f, 0.f, 0.f, 0.f};
    f32x4 lacc[2] = {(f32x4){0.f, 0.f, 0.f, 0.f}, (f32x4){0.f, 0.f, 0.f, 0.f}};

    // stage tile 0 into buf0
#pragma unroll
    for (int it = 0; it < 4; ++it) {
        async_copy16(gK + it * 16384, base + ldsSt + it * 8192);
        async_copy16(gV + it * 262144, base + 32768 + ldsSt + it * 8192);
    }
    __syncthreads();

    const int hK = kg * 16384, hV = kg * 128;  // this wave's 64-key half

    for (int i = 0; i < 32; ++i) {
        char* KtB = base + (i & 1) * 65536;
        char* VtB = KtB + 32768;
        if (i < 31) {  // issue async loads for next tile into other buffer
            char* Kd = base + (((i & 1) ^ 1) * 65536) + ldsSt;
            size_t m = (size_t)(i + 1) * 128;
#pragma unroll
            for (int it = 0; it < 4; ++it) {
                async_copy16(gK + m * 512 + it * 16384, Kd + it * 8192);
                async_copy16(gV + m * 2 + it * 262144, Kd + 32768 + it * 8192);
            }
        }

        // S^T = mfma(K, Q): D[row=key kg*64+tc*16+4q+r][col=query s]
        f32x4 sa[2][4];
#pragma unroll
        for (int fr = 0; fr < 2; ++fr)
#pragma unroll
            for (int tc = 0; tc < 4; ++tc) sa[fr][tc] = (f32x4){0.f, 0.f, 0.f, 0.f};
        __builtin_amdgcn_s_setprio(1);
#pragma unroll
        for (int tc = 0; tc < 4; ++tc) {
            bf16x8 bfv[4];
#pragma unroll
            for (int kb = 0; kb < 4; ++kb)
                bfv[kb] = *(const bf16x8*)(KtB + hK + kA[kb] + tc * 4096);
#pragma unroll
            for (int fr = 0; fr < 2; ++fr)
#pragma unroll
                for (int kb = 0; kb < 4; ++kb)
                    sa[fr][tc] = __builtin_amdgcn_mfma_f32_16x16x32_bf16(bfv[kb], qf[fr][kb], sa[fr][tc], 0, 0, 0);
        }
        __builtin_amdgcn_s_setprio(0);

        // P = exp2(S), pack pairs (keys 2p,2p+1)
        unsigned W[2][4][2];
#pragma unroll
        for (int fr = 0; fr < 2; ++fr) {
#pragma unroll
            for (int tc = 0; tc < 4; ++tc)
#pragma unroll
                for (int r = 0; r < 4; ++r) sa[fr][tc][r] = exp2f(sa[fr][tc][r]);
#pragma unroll
            for (int tc = 0; tc < 4; ++tc) {
                W[fr][tc][0] = cvt_pk_bf16(sa[fr][tc][0], sa[fr][tc][1]);
                W[fr][tc][1] = cvt_pk_bf16(sa[fr][tc][2], sa[fr][tc][3]);
            }
        }

        // PV: redistribute P pairs in-register; l via ones-MFMA; O += P*V^T
#pragma unroll
        for (int kb2 = 0; kb2 < 2; ++kb2) {
            bf16x8 pa[2];
#pragma unroll
            for (int fr = 0; fr < 2; ++fr) {
                unsigned rA = W[fr][2 * kb2 + 0][0];
                unsigned rB = W[fr][2 * kb2 + 0][1];
                unsigned rC = W[fr][2 * kb2 + 1][0];
                unsigned rD = W[fr][2 * kb2 + 1][1];
                asm("v_permlane32_swap_b32 %0, %1" : "+v"(rA), "+v"(rC));
                asm("v_permlane32_swap_b32 %0, %1" : "+v"(rB), "+v"(rD));
                asm("v_permlane16_swap_b32 %0, %1" : "+v"(rA), "+v"(rC));
                asm("v_permlane16_swap_b32 %0, %1" : "+v"(rB), "+v"(rD));
                i32x4 wv = (i32x4){(int)rA, (int)rB, (int)rC, (int)rD};
                pa[fr] = __builtin_bit_cast(bf16x8, wv);
            }
            __builtin_amdgcn_s_setprio(1);
            lacc[0] = __builtin_amdgcn_mfma_f32_16x16x32_bf16(pa[0], vone, lacc[0], 0, 0, 0);
            lacc[1] = __builtin_amdgcn_mfma_f32_16x16x32_bf16(pa[1], vone, lacc[1], 0, 0, 0);
#pragma unroll
            for (int t = 0; t < 8; ++t) {
                bf16x8 vb = *(const bf16x8*)(VtB + hV + vA[kb2] + t * 4096);
                ot[0][t] = __builtin_amdgcn_mfma_f32_16x16x32_bf16(pa[0], vb, ot[0][t], 0, 0, 0);
                ot[1][t] = __builtin_amdgcn_mfma_f32_16x16x32_bf16(pa[1], vb, ot[1][t], 0, 0, 0);
            }
            __builtin_amdgcn_s_setprio(0);
        }
        __syncthreads();  // implicit vmcnt(0) drain covers this iter's async loads
    }

    // ---- epilogue: cross-kg O reduction, y->LDS, in-block wy GEMM ----
    if (s == 0) {
#pragma unroll
        for (int fr = 0; fr < 2; ++fr)
#pragma unroll
            for (int r = 0; r < 4; ++r)
                l_lds[kg][qg * 32 + fr * 16 + 4 * q + r] = lacc[fr][r];
    }
    // kg=1 dumps O partials (f32, swizzled 16B blocks) into base[0..64KB)
    if (kg == 1) {
#pragma unroll
        for (int fr = 0; fr < 2; ++fr)
#pragma unroll
            for (int t = 0; t < 8; ++t)
#pragma unroll
                for (int r = 0; r < 4; ++r) {
                    int row = qg * 32 + fr * 16 + 4 * q + r;
                    int colb = (t * 16 + s) * 4;
                    *(float*)(base + row * 512 + (colb ^ ((row & 7) << 4))) = ot[fr][t][r];
                }
    }
    __syncthreads();
    // kg=0 adds partials, writes unnormalized y bf16 -> base[65536..98304)
    if (kg == 0) {
#pragma unroll
        for (int fr = 0; fr < 2; ++fr)
#pragma unroll
            for (int t = 0; t < 8; ++t)
#pragma unroll
                for (int r = 0; r < 4; ++r) {
                    int row = qg * 32 + fr * 16 + 4 * q + r;
                    int colb = (t * 16 + s) * 4;
                    float p = *(const float*)(base + row * 512 + (colb ^ ((row & 7) << 4)));
                    float v = ot[fr][t][r] + p;
                    int byt = 65536 + row * 256 + (((t * 16 + s) * 2) ^ ((row & 7) << 4));
                    *(short*)(base + byt) = f2bf(v);
                }
    }
    __syncthreads();

    // wy GEMM: c = wave*32 + ct*16 + {s|4q+r}, n = n0 + jt*16 + s
    f32x4 acc[2][8];
#pragma unroll
    for (int ct = 0; ct < 2; ++ct)
#pragma unroll
        for (int jt = 0; jt < 8; ++jt) acc[ct][jt] = (f32x4){0.f, 0.f, 0.f, 0.f};
#pragma unroll
    for (int kb = 0; kb < 4; ++kb) {
        bf16x8 af[2];
#pragma unroll
        for (int ct = 0; ct < 2; ++ct)
            af[ct] = *(const bf16x8*)&wwb[(wave * 32 + ct * 16 + s) * 128 + kb * 32 + q * 8];
#pragma unroll
        for (int jt = 0; jt < 8; ++jt) {
            bf16x8 yb = *(const bf16x8*)(base + 65536 + kA[kb] + jt * 4096);
#pragma unroll
            for (int ct = 0; ct < 2; ++ct)
                acc[ct][jt] = __builtin_amdgcn_mfma_f32_16x16x32_bf16(af[ct], yb, acc[ct][jt], 0, 0, 0);
        }
    }
    float linv[8];
#pragma unroll
    for (int jt = 0; jt < 8; ++jt)
        linv[jt] = 1.0f / (l_lds[0][jt * 16 + s] + l_lds[1][jt * 16 + s]);
#pragma unroll
    for (int ct = 0; ct < 2; ++ct)
#pragma unroll
        for (int r = 0; r < 4; ++r) {
            int c = wave * 32 + ct * 16 + 4 * q + r;
            float bias = w_b[c];
            float s1 = 0.f, s2 = 0.f;
#pragma unroll
            for (int jt = 0; jt < 8; ++jt) {
                float v = acc[ct][jt][r] * linv[jt] + bias;
                short w = f2bf(v);
                wyh[((size_t)b * C_ + c) * N_ + n0 + jt * 16 + s] = w;
                float vr = bf2f(w);   // stats on rounded value == old k_stats
                s1 += vr;
                s2 += vr * vr;
            }
#pragma unroll
            for (int off = 1; off < 16; off <<= 1) {
                s1 += __shfl_xor(s1, off);
                s2 += __shfl_xor(s2, off);
            }
            if (s == 0) {
                atomicAdd(&bnsum[c], s1);
                atomicAdd(&bnsum[256 + c], s2);
            }
        }
}

// ---------------- K5: BN finalize + apply + residual -> d_out f32 ------------
__global__ __launch_bounds__(256) void k_out(const short* __restrict__ wyh,
                                             const float* __restrict__ x,
                                             const float* __restrict__ bnsum,
                                             const float* __restrict__ gamma,
                                             const float* __restrict__ beta,
                                             float* __restrict__ out) {
    int gid = blockIdx.x * 256 + threadIdx.x;  // 8-element group index
    size_t base = (size_t)gid * 8;
    int c = (int)((base >> 12) & 255);
    const float inv = 1.0f / 32768.0f;
    float mean = bnsum[c] * inv;
    float var = bnsum[256 + c] * inv - mean * mean;
    float sc = gamma[c] * rsqrtf(var + 1e-5f);
    float sh = beta[c] - mean * sc;
    bf16x8 w = *(const bf16x8*)&wyh[base];
    float4 x0 = *(const float4*)&x[base];
    float4 x1 = *(const float4*)&x[base + 4];
    float4 o0, o1;
    o0.x = bf2f(w[0]) * sc + sh + x0.x;
    o0.y = bf2f(w[1]) * sc + sh + x0.y;
    o0.z = bf2f(w[2]) * sc + sh + x0.z;
    o0.w = bf2f(w[3]) * sc + sh + x0.w;
    o1.x = bf2f(w[4]) * sc + sh + x1.x;
    o1.y = bf2f(w[5]) * sc + sh + x1.y;
    o1.z = bf2f(w[6]) * sc + sh + x1.z;
    o1.w = bf2f(w[7]) * sc + sh + x1.w;
    *(float4*)&out[base] = o0;
    *(float4*)&out[base + 4] = o1;
}

extern "C" void kernel_launch(void* const* d_in, const int* in_sizes, int n_in,
                              void* d_out, int out_size, void* d_ws, size_t ws_size,
                              hipStream_t stream) {
    const float* x       = (const float*)d_in[0];
    const float* g_w     = (const float*)d_in[1];
    const float* g_b     = (const float*)d_in[2];
    const float* theta_w = (const float*)d_in[3];
    const float* theta_b = (const float*)d_in[4];
    const float* phi_w   = (const float*)d_in[5];
    const float* phi_b   = (const float*)d_in[6];
    const float* w_w     = (const float*)d_in[7];
    const float* w_b     = (const float*)d_in[8];
    const float* gamma   = (const float*)d_in[9];
    const float* beta    = (const float*)d_in[10];

    char* ws = (char*)d_ws;
    size_t off = 0;
    auto alloc = [&](size_t bytes) {
        void* p = ws + off;
        off += (bytes + 255) & ~(size_t)255;
        return p;
    };
    short*  wcat  = (short*)alloc((size_t)384 * 256 * 2);
    short*  wwb   = (short*)alloc((size_t)256 * 128 * 2);
    float*  bcat  = (float*)alloc((size_t)384 * 4);
    float*  bnsum = (float*)alloc(512 * 4);                  // s1[256] | s2[256]
    short*  tp    = (short*)alloc((size_t)BN_ * 256 * 2);    // theta|phi 16.78 MB
    short*  gmat  = (short*)alloc((size_t)B_ * I_ * N_ * 2); // 8.39 MB
    short*  wyh   = (short*)alloc((size_t)BN_ * C_ * 2);     // bf16 wy 16.78 MB

    k_prep<<<516, 256, 0, stream>>>(g_w, theta_w, phi_w, g_b, theta_b, phi_b, w_w,
                                    wcat, wwb, bcat, bnsum);
    k_proj<<<dim3(64, 8), 256, 0, stream>>>(x, wcat, bcat, tp, gmat);
    k_attn_wy<<<256, 512, 0, stream>>>(tp, gmat, wwb, w_b, wyh, bnsum);
    k_out<<<4096, 256, 0, stream>>>(wyh, x, bnsum, gamma, beta, (float*)d_out);
}